// Round 9
// baseline (428.890 us; speedup 1.0000x reference)
//
#include <hip/hip_runtime.h>
#include <hip/hip_bf16.h>
#include <stdint.h>

typedef __bf16 bf16;
typedef bf16 bf16x8 __attribute__((ext_vector_type(8)));
typedef bf16 bf16x4 __attribute__((ext_vector_type(4)));
typedef float f32x4 __attribute__((ext_vector_type(4)));

#define MFMA16(a, b, c) __builtin_amdgcn_mfma_f32_16x16x32_bf16((a), (b), (c), 0, 0, 0)

// async 16B global->LDS (wave-uniform LDS base, per-lane global src)
__device__ __forceinline__ void async_ld16(bf16* lds, const bf16* g) {
    __builtin_amdgcn_global_load_lds(
        (const __attribute__((address_space(1))) void*)g,
        (__attribute__((address_space(3))) void*)lds, 16, 0, 0);
}

// ---------------------------------------------------------------------------
// Kernel 1: QKV projection.  C[M,N] = X[M,K] * W[N,K]^T  (x @ W.T), bf16 out.
// z = 0 -> Q (row-major), z = 1 -> K (row-major), z = 2 -> V transposed
// (Vt[b][e][s]) so the attention kernel's PV B-fragments are contiguous.
// ---------------------------------------------------------------------------
__global__ __launch_bounds__(256) void proj_kernel(
    const float* __restrict__ X,
    const float* __restrict__ Wq,
    const float* __restrict__ Wk,
    const float* __restrict__ Wv,
    bf16* __restrict__ Qo,
    bf16* __restrict__ Ko,
    bf16* __restrict__ Vt)
{
    __shared__ bf16 As[128][72];
    __shared__ bf16 Bs[128][72];

    const int z    = blockIdx.z;
    const float* W = (z == 0) ? Wq : (z == 1) ? Wk : Wv;
    const int row0 = blockIdx.x * 128;
    const int col0 = blockIdx.y * 128;

    const int t    = threadIdx.x;
    const int w    = t >> 6;
    const int lane = t & 63;
    const int lg   = lane >> 4;
    const int lc   = lane & 15;
    const int wr   = (w >> 1) * 64;
    const int wc   = (w & 1) * 64;

    const int srow = t >> 1;
    const int sd0  = (t & 1) * 16;

    f32x4 acc[4][4];
    for (int a = 0; a < 4; ++a)
        for (int b = 0; b < 4; ++b)
            acc[a][b] = (f32x4){0.f, 0.f, 0.f, 0.f};

    for (int kt = 0; kt < 16; ++kt) {
        const int k = kt * 32;
        __syncthreads();
        {
            const float* xs = X + (size_t)(row0 + srow) * 512 + k + sd0;
            float4 a0 = *(const float4*)(xs + 0);
            float4 a1 = *(const float4*)(xs + 4);
            float4 a2 = *(const float4*)(xs + 8);
            float4 a3 = *(const float4*)(xs + 12);
            bf16x8 h0 = { (bf16)a0.x, (bf16)a0.y, (bf16)a0.z, (bf16)a0.w,
                          (bf16)a1.x, (bf16)a1.y, (bf16)a1.z, (bf16)a1.w };
            bf16x8 h1 = { (bf16)a2.x, (bf16)a2.y, (bf16)a2.z, (bf16)a2.w,
                          (bf16)a3.x, (bf16)a3.y, (bf16)a3.z, (bf16)a3.w };
            *(bf16x8*)&As[srow][sd0]     = h0;
            *(bf16x8*)&As[srow][sd0 + 8] = h1;

            const float* ws_ = W + (size_t)(col0 + srow) * 512 + k + sd0;
            float4 b0 = *(const float4*)(ws_ + 0);
            float4 b1 = *(const float4*)(ws_ + 4);
            float4 b2 = *(const float4*)(ws_ + 8);
            float4 b3 = *(const float4*)(ws_ + 12);
            bf16x8 g0 = { (bf16)b0.x, (bf16)b0.y, (bf16)b0.z, (bf16)b0.w,
                          (bf16)b1.x, (bf16)b1.y, (bf16)b1.z, (bf16)b1.w };
            bf16x8 g1 = { (bf16)b2.x, (bf16)b2.y, (bf16)b2.z, (bf16)b2.w,
                          (bf16)b3.x, (bf16)b3.y, (bf16)b3.z, (bf16)b3.w };
            *(bf16x8*)&Bs[srow][sd0]     = g0;
            *(bf16x8*)&Bs[srow][sd0 + 8] = g1;
        }
        __syncthreads();

        bf16x8 af[4], bfr[4];
        for (int fr = 0; fr < 4; ++fr)
            af[fr] = *(const bf16x8*)&As[wr + fr * 16 + lc][lg * 8];
        for (int fc = 0; fc < 4; ++fc)
            bfr[fc] = *(const bf16x8*)&Bs[wc + fc * 16 + lc][lg * 8];
        for (int fr = 0; fr < 4; ++fr)
            for (int fc = 0; fc < 4; ++fc)
                acc[fr][fc] = MFMA16(af[fr], bfr[fc], acc[fr][fc]);
    }

    if (z < 2) {
        bf16* outp = (z == 0) ? Qo : Ko;
        for (int fr = 0; fr < 4; ++fr)
            for (int fc = 0; fc < 4; ++fc) {
                const int colg = col0 + wc + fc * 16 + lc;
                const int rowb = row0 + wr + fr * 16 + lg * 4;
                for (int i = 0; i < 4; ++i)
                    outp[(size_t)(rowb + i) * 512 + colg] = (bf16)acc[fr][fc][i];
            }
    } else {
        for (int fr = 0; fr < 4; ++fr)
            for (int fc = 0; fc < 4; ++fc) {
                const int e    = col0 + wc + fc * 16 + lc;
                const int rowb = row0 + wr + fr * 16 + lg * 4;
                const int bb   = rowb >> 12;
                const int sl   = rowb & 4095;
                bf16x4 v = { (bf16)acc[fr][fc][0], (bf16)acc[fr][fc][1],
                             (bf16)acc[fr][fc][2], (bf16)acc[fr][fc][3] };
                *(bf16x4*)&Vt[(((size_t)(bb * 512 + e)) << 12) + sl] = v;
            }
    }
}

// ---------------------------------------------------------------------------
// Kernel 2: flash attention, no-max softmax.  TWO INDEPENDENT BLOCKS PER CU:
// 256 threads (4 waves), q-tile 32, kv-tile 64, single K LDS buffer (64 KiB),
// 3-barrier counted-vmcnt schedule, P [32][72] -> 70 KiB LDS -> 2 blocks/CU
// whose barrier groups hide each other's serial phases.
// Per iter: issue all 16 V b128 -> vmcnt(16) [K(i) landed, V in flight] ->
// bar1 -> QK from LDS -> lgkmcnt(0) [ALL LDS reads arch-complete: QK's K
// reads AND prev PV's P reads — REQUIRED before any wave may overwrite
// Kb/Pb; bar2 alone only proves arrival, not read completion (R8 race)] ->
// bar2 -> issue K(i+1) (16x gld_lds) -> exp/P-write -> lgkmcnt(0) -> bar3 ->
// PV (V regs).  vmcnt never drains to 0 inside the loop.
// __launch_bounds__(256,2): VGPR cap 256 (working set ~230, no spill).
// ---------------------------------------------------------------------------
__global__ __launch_bounds__(256, 2) void flash_kernel(
    const bf16* __restrict__ Q,
    const bf16* __restrict__ K,
    const bf16* __restrict__ Vt,
    const float* __restrict__ temp,
    float* __restrict__ Out)
{
    extern __shared__ char smem[];
    bf16* Kb = (bf16*)smem;                   // [64*512]  64 KiB (single buf)
    bf16* Pb = (bf16*)(smem + 64 * 512 * 2);  // [32*72]   4.5 KiB
    __shared__ float l_part[32][2];

    // XCD-aware decode (bijective): XCD = L&7, batch = (L&7)>>1,
    // q-index = (L&1)*64 + (L>>3) in 0..127 -> q0 = 32*q-index.
    const int L  = blockIdx.x;
    const int b  = (L & 7) >> 1;
    const int q0 = (((L & 1) << 6) + (L >> 3)) << 5;

    const int t    = threadIdx.x;          // 0..255
    const int w    = t >> 6;               // wave 0..3
    const int lane = t & 63;
    const int lg   = lane >> 4;
    const int lc   = lane & 15;
    const int qrb  = (w >> 1) * 16;        // q-row block (0 or 16)
    const int par  = w & 1;                // key-col parity (32 keys each)

    const float scale2 = temp[0] * 0.04419417382415922f * 1.4426950408889634f;

    const bf16* kbase = K  + (size_t)b * 4096 * 512;
    const bf16* vbase = Vt + (size_t)b * 512 * 4096;

    // prologue: stage K tile 0 (wave w stages rows w*16..w*16+15, swizzled src)
#pragma unroll
    for (int j = 0; j < 16; ++j) {
        const int r = w * 16 + j;                     // r&7 == j&7
        async_ld16(Kb + (size_t)r * 512,
                   kbase + (size_t)r * 512 + ((lane ^ (j & 7)) << 3));
    }

    // Q fragments, register-resident: rows q0+qrb+lc, full d=512  (64 VGPR)
    bf16x8 qf[16];
    {
        const bf16* qrow = Q + ((size_t)(b * 4096 + q0 + qrb + lc)) * 512 + lg * 8;
#pragma unroll
        for (int kt = 0; kt < 16; ++kt)
            qf[kt] = *(const bf16x8*)(qrow + kt * 32);
    }

    // O accumulator: 32 q-rows x 128 e-cols (this wave's e chunk)  (64 VGPR)
    f32x4 acc[2][8];
    for (int a = 0; a < 2; ++a)
        for (int c = 0; c < 8; ++c)
            acc[a][c] = (f32x4){0.f, 0.f, 0.f, 0.f};
    float Lacc[4] = {0.f, 0.f, 0.f, 0.f};

    __syncthreads();   // full drain: K tile 0 + qf resident

    // read-side swizzle constants (row_local & 7 == lc & 7 for both K rows)
    const int r7  = lc & 7;
    const int xlo = (lg ^ (r7 & 3)) << 3;
    const int xb2 = (r7 & 4) << 3;

    for (int it = 0; it < 64; ++it) {
        // ---- issue ALL V loads for THIS tile (fly through QK phase) ----
        // wave's V slice: e in [w*128, w*128+128), k in [it*64, it*64+64)
        const bf16* vb0 = vbase + (size_t)(w * 128 + lc) * 4096 + it * 64 + lg * 8;
        bf16x8 vv[16];                      // 64 VGPR
#pragma unroll
        for (int kk2 = 0; kk2 < 2; ++kk2)
#pragma unroll
            for (int fc = 0; fc < 8; ++fc)
                vv[kk2 * 8 + fc] =
                    *(const bf16x8*)(vb0 + (size_t)fc * 16 * 4096 + kk2 * 32);

        // ---- K(i) landed: outstanding = K(i)16 + V16 -> wait to 16 ----
        asm volatile("s_waitcnt vmcnt(16)" ::: "memory");
        __builtin_amdgcn_s_barrier();

        // ---- S = Q K^T from LDS (swizzled ds_read_b128) ----
        f32x4 s0 = (f32x4){0.f, 0.f, 0.f, 0.f};
        f32x4 s1 = (f32x4){0.f, 0.f, 0.f, 0.f};
        const bf16* kr0 = Kb + (size_t)(par * 32 + lc) * 512 + xlo;
        const bf16* kr1 = kr0 + (size_t)16 * 512;
#pragma unroll
        for (int kt = 0; kt < 16; ++kt) {
            const int off = (kt * 32) ^ xb2;
            bf16x8 k0 = *(const bf16x8*)(kr0 + off);
            bf16x8 k1 = *(const bf16x8*)(kr1 + off);
            s0 = MFMA16(qf[kt], k0, s0);
            s1 = MFMA16(qf[kt], k1, s1);
        }

        // ---- RACE FIX (R8): architecturally complete ALL of this wave's
        // LDS reads (QK's K reads + previous PV's P reads) BEFORE the
        // barrier that licenses overwriting Kb (prefetch) and Pb (exp).
        asm volatile("s_waitcnt lgkmcnt(0)" ::: "memory");
        __builtin_amdgcn_s_barrier();

        // ---- issue K(i+1) prefetch into the (now free) single buffer ----
        {
            const int nxt = (it + 1) & 63;          // last iter: discarded
            const bf16* knx = kbase + (size_t)nxt * 64 * 512;
#pragma unroll
            for (int j = 0; j < 16; ++j) {
                const int r = w * 16 + j;
                async_ld16(Kb + (size_t)r * 512,
                           knx + (size_t)r * 512 + ((lane ^ (j & 7)) << 3));
            }
        }

        // ---- P = exp2(s*scale2) -> LDS, accumulate denominator ----
#pragma unroll
        for (int i = 0; i < 4; ++i) {
            const int row = qrb + lg * 4 + i;
            float p0 = __builtin_amdgcn_exp2f(s0[i] * scale2);
            float p1 = __builtin_amdgcn_exp2f(s1[i] * scale2);
            Pb[row * 72 + par * 32 + lc]      = (bf16)p0;
            Pb[row * 72 + par * 32 + 16 + lc] = (bf16)p1;
            Lacc[i] += p0 + p1;
        }

        // ---- P visible; K(i+1) still in flight (vmcnt untouched) ----
        asm volatile("s_waitcnt lgkmcnt(0)" ::: "memory");
        __builtin_amdgcn_s_barrier();

        // ---- O += P * V (V regs: compiler waits leave K(i+1) in flight) ----
#pragma unroll
        for (int kk2 = 0; kk2 < 2; ++kk2) {
            bf16x8 pa[2];
#pragma unroll
            for (int fr = 0; fr < 2; ++fr)
                pa[fr] = *(const bf16x8*)&Pb[(fr * 16 + lc) * 72 + kk2 * 32 + lg * 8];
#pragma unroll
            for (int fc = 0; fc < 8; ++fc)
#pragma unroll
                for (int fr = 0; fr < 2; ++fr)
                    acc[fr][fc] = MFMA16(pa[fr], vv[kk2 * 8 + fc], acc[fr][fc]);
        }
    }

    // ---- denominator: reduce per-lane partials across the 16 lc lanes ----
#pragma unroll
    for (int d = 1; d < 16; d <<= 1)
#pragma unroll
        for (int i = 0; i < 4; ++i)
            Lacc[i] += __shfl_xor(Lacc[i], d);
    if (lc == 0)
#pragma unroll
        for (int i = 0; i < 4; ++i)
            l_part[qrb + lg * 4 + i][par] = Lacc[i];
    __syncthreads();   // l_part visible; also drains the final discarded prefetch

    // ---- epilogue: divide by denominator, store fp32 ----
    for (int fr = 0; fr < 2; ++fr) {
        float invl[4];
#pragma unroll
        for (int i = 0; i < 4; ++i) {
            const int row = fr * 16 + lg * 4 + i;
            invl[i] = 1.0f / (l_part[row][0] + l_part[row][1]);
        }
        for (int fc = 0; fc < 8; ++fc) {
            const size_t base =
                ((size_t)(b * 4096 + q0 + fr * 16 + lg * 4)) * 512 + w * 128 + fc * 16 + lc;
#pragma unroll
            for (int i = 0; i < 4; ++i)
                Out[base + (size_t)i * 512] = acc[fr][fc][i] * invl[i];
        }
    }
}

// ---------------------------------------------------------------------------
extern "C" void kernel_launch(void* const* d_in, const int* in_sizes, int n_in,
                              void* d_out, int out_size, void* d_ws, size_t ws_size,
                              hipStream_t stream) {
    const float* X    = (const float*)d_in[0];
    const float* Wq   = (const float*)d_in[1];
    const float* Wk   = (const float*)d_in[2];
    const float* Wv   = (const float*)d_in[3];
    const float* temp = (const float*)d_in[4];
    float* Out = (float*)d_out;

    const size_t NE = (size_t)4 * 4096 * 512;
    bf16* Qw = (bf16*)d_ws;
    bf16* Kw = Qw + NE;
    bf16* Vt = Kw + NE;

    proj_kernel<<<dim3(128, 4, 3), 256, 0, stream>>>(X, Wq, Wk, Wv, Qw, Kw, Vt);

    // dynamic LDS: K 64 KiB + P 4.5 KiB = 70144 B -> 2 blocks/CU (140 KiB)
    const size_t smem_bytes = (size_t)64 * 512 * 2 + (size_t)32 * 72 * 2;
    flash_kernel<<<dim3(512), 256, smem_bytes, stream>>>(Qw, Kw, Vt, temp, Out);
}

// Round 10
// 287.172 us; speedup vs baseline: 1.4935x; 1.4935x over previous
//
#include <hip/hip_runtime.h>
#include <hip/hip_bf16.h>
#include <stdint.h>

typedef __bf16 bf16;
typedef bf16 bf16x8 __attribute__((ext_vector_type(8)));
typedef bf16 bf16x4 __attribute__((ext_vector_type(4)));
typedef float f32x4 __attribute__((ext_vector_type(4)));

#define MFMA16(a, b, c) __builtin_amdgcn_mfma_f32_16x16x32_bf16((a), (b), (c), 0, 0, 0)

// async 16B global->LDS (wave-uniform LDS base, per-lane global src)
__device__ __forceinline__ void async_ld16(bf16* lds, const bf16* g) {
    __builtin_amdgcn_global_load_lds(
        (const __attribute__((address_space(1))) void*)g,
        (__attribute__((address_space(3))) void*)lds, 16, 0, 0);
}

// ---------------------------------------------------------------------------
// Kernel 1: QKV projection.  C[M,N] = X[M,K] * W[N,K]^T  (x @ W.T), bf16 out.
// z = 0 -> Q (row-major), z = 1 -> K (row-major), z = 2 -> V transposed
// (Vt[b][e][s]) so the attention kernel's PV B-fragments are contiguous.
// ---------------------------------------------------------------------------
__global__ __launch_bounds__(256) void proj_kernel(
    const float* __restrict__ X,
    const float* __restrict__ Wq,
    const float* __restrict__ Wk,
    const float* __restrict__ Wv,
    bf16* __restrict__ Qo,
    bf16* __restrict__ Ko,
    bf16* __restrict__ Vt)
{
    __shared__ bf16 As[128][72];
    __shared__ bf16 Bs[128][72];

    const int z    = blockIdx.z;
    const float* W = (z == 0) ? Wq : (z == 1) ? Wk : Wv;
    const int row0 = blockIdx.x * 128;
    const int col0 = blockIdx.y * 128;

    const int t    = threadIdx.x;
    const int w    = t >> 6;
    const int lane = t & 63;
    const int lg   = lane >> 4;
    const int lc   = lane & 15;
    const int wr   = (w >> 1) * 64;
    const int wc   = (w & 1) * 64;

    const int srow = t >> 1;
    const int sd0  = (t & 1) * 16;

    f32x4 acc[4][4];
    for (int a = 0; a < 4; ++a)
        for (int b = 0; b < 4; ++b)
            acc[a][b] = (f32x4){0.f, 0.f, 0.f, 0.f};

    for (int kt = 0; kt < 16; ++kt) {
        const int k = kt * 32;
        __syncthreads();
        {
            const float* xs = X + (size_t)(row0 + srow) * 512 + k + sd0;
            float4 a0 = *(const float4*)(xs + 0);
            float4 a1 = *(const float4*)(xs + 4);
            float4 a2 = *(const float4*)(xs + 8);
            float4 a3 = *(const float4*)(xs + 12);
            bf16x8 h0 = { (bf16)a0.x, (bf16)a0.y, (bf16)a0.z, (bf16)a0.w,
                          (bf16)a1.x, (bf16)a1.y, (bf16)a1.z, (bf16)a1.w };
            bf16x8 h1 = { (bf16)a2.x, (bf16)a2.y, (bf16)a2.z, (bf16)a2.w,
                          (bf16)a3.x, (bf16)a3.y, (bf16)a3.z, (bf16)a3.w };
            *(bf16x8*)&As[srow][sd0]     = h0;
            *(bf16x8*)&As[srow][sd0 + 8] = h1;

            const float* ws_ = W + (size_t)(col0 + srow) * 512 + k + sd0;
            float4 b0 = *(const float4*)(ws_ + 0);
            float4 b1 = *(const float4*)(ws_ + 4);
            float4 b2 = *(const float4*)(ws_ + 8);
            float4 b3 = *(const float4*)(ws_ + 12);
            bf16x8 g0 = { (bf16)b0.x, (bf16)b0.y, (bf16)b0.z, (bf16)b0.w,
                          (bf16)b1.x, (bf16)b1.y, (bf16)b1.z, (bf16)b1.w };
            bf16x8 g1 = { (bf16)b2.x, (bf16)b2.y, (bf16)b2.z, (bf16)b2.w,
                          (bf16)b3.x, (bf16)b3.y, (bf16)b3.z, (bf16)b3.w };
            *(bf16x8*)&Bs[srow][sd0]     = g0;
            *(bf16x8*)&Bs[srow][sd0 + 8] = g1;
        }
        __syncthreads();

        bf16x8 af[4], bfr[4];
        for (int fr = 0; fr < 4; ++fr)
            af[fr] = *(const bf16x8*)&As[wr + fr * 16 + lc][lg * 8];
        for (int fc = 0; fc < 4; ++fc)
            bfr[fc] = *(const bf16x8*)&Bs[wc + fc * 16 + lc][lg * 8];
        for (int fr = 0; fr < 4; ++fr)
            for (int fc = 0; fc < 4; ++fc)
                acc[fr][fc] = MFMA16(af[fr], bfr[fc], acc[fr][fc]);
    }

    if (z < 2) {
        bf16* outp = (z == 0) ? Qo : Ko;
        for (int fr = 0; fr < 4; ++fr)
            for (int fc = 0; fc < 4; ++fc) {
                const int colg = col0 + wc + fc * 16 + lc;
                const int rowb = row0 + wr + fr * 16 + lg * 4;
                for (int i = 0; i < 4; ++i)
                    outp[(size_t)(rowb + i) * 512 + colg] = (bf16)acc[fr][fc][i];
            }
    } else {
        for (int fr = 0; fr < 4; ++fr)
            for (int fc = 0; fc < 4; ++fc) {
                const int e    = col0 + wc + fc * 16 + lc;
                const int rowb = row0 + wr + fr * 16 + lg * 4;
                const int bb   = rowb >> 12;
                const int sl   = rowb & 4095;
                bf16x4 v = { (bf16)acc[fr][fc][0], (bf16)acc[fr][fc][1],
                             (bf16)acc[fr][fc][2], (bf16)acc[fr][fc][3] };
                *(bf16x4*)&Vt[(((size_t)(bb * 512 + e)) << 12) + sl] = v;
            }
    }
}

// ---------------------------------------------------------------------------
// Kernel 2: flash attention (R3 structure, verbatim, + QK chain-split).
// K tiles staged in LDS (double-buffered, global_load_lds, XOR-swizzled via
// pre-swizzled per-lane SOURCE address — LDS dest stays linear).
// Per iter: [issue K-prefetch(i+1) | issue V loads(i) | QK^T from LDS with
// FOUR independent MFMA accumulator chains | exp/P-write | __syncthreads
// (drains prefetch) | PV from regs+P_lds].
// ---------------------------------------------------------------------------
__global__ __launch_bounds__(512) void flash_kernel(
    const bf16* __restrict__ Q,
    const bf16* __restrict__ K,
    const bf16* __restrict__ Vt,
    const float* __restrict__ temp,
    float* __restrict__ Out)
{
    extern __shared__ char smem[];
    bf16* Kb = (bf16*)smem;                       // [2][64*512]  128 KiB
    bf16* Pb = (bf16*)(smem + 2 * 64 * 512 * 2);  // [2][64*72]   18 KiB
    __shared__ float l_part[64][2];

    const int b  = blockIdx.y;
    const int q0 = blockIdx.x * 64;
    const int t    = threadIdx.x;
    const int w    = t >> 6;
    const int lane = t & 63;
    const int lg   = lane >> 4;
    const int lc   = lane & 15;
    const int qrb  = (w >> 1) * 16;
    const int par  = w & 1;

    const float scale2 = temp[0] * 0.04419417382415922f * 1.4426950408889634f;

    const bf16* kbase = K  + (size_t)b * 4096 * 512;
    const bf16* vbase = Vt + (size_t)b * 512 * 4096;

    // Q fragments, register-resident for the whole kernel
    bf16x8 qf[16];
    {
        const bf16* qrow = Q + ((size_t)(b * 4096 + q0 + qrb + lc)) * 512 + lg * 8;
#pragma unroll
        for (int kt = 0; kt < 16; ++kt)
            qf[kt] = *(const bf16x8*)(qrow + kt * 32);
    }

    f32x4 acc[4][4];
    for (int a = 0; a < 4; ++a)
        for (int c = 0; c < 4; ++c)
            acc[a][c] = (f32x4){0.f, 0.f, 0.f, 0.f};
    float Lacc[4] = {0.f, 0.f, 0.f, 0.f};

    // prologue: stage K tile 0 into buf 0 (wave w stages rows w*8..w*8+7)
#pragma unroll
    for (int j = 0; j < 8; ++j) {
        const int r = w * 8 + j;                      // r&7 == j
        async_ld16(Kb + (size_t)r * 512,
                   kbase + (size_t)r * 512 + ((lane ^ j) << 3));
    }
    __syncthreads();   // vmcnt(0) drain -> tile 0 resident

    // read-side swizzle constants (row_local & 7 == lc & 7 for both K rows)
    const int r7  = lc & 7;
    const int xlo = (lg ^ (r7 & 3)) << 3;   // element offset from lg, low bits
    const int xb2 = (r7 & 4) << 3;          // XOR 0/32 elements on kt*32

    for (int kv0 = 0; kv0 < 4096; kv0 += 64) {
        const int cur = (kv0 >> 6) & 1;
        const bf16* Kc = Kb + (size_t)cur * 32768;
        bf16*       Pc = Pb + (size_t)cur * (64 * 72);

        // ---- issue next K-tile prefetch (in flight through QK+exp) ----
        if (kv0 + 64 < 4096) {
            bf16* Kn = Kb + (size_t)(cur ^ 1) * 32768;
            const bf16* knx = kbase + (size_t)(kv0 + 64) * 512;
#pragma unroll
            for (int j = 0; j < 8; ++j) {
                const int r = w * 8 + j;
                async_ld16(Kn + (size_t)r * 512,
                           knx + (size_t)r * 512 + ((lane ^ j) << 3));
            }
        }

        // ---- issue V loads for THIS tile (consumed after the barrier) ----
        const bf16* vb0 = vbase + (size_t)(w * 64 + lc) * 4096 + kv0 + lg * 8;
        bf16x8 vv[8];
#pragma unroll
        for (int kk2 = 0; kk2 < 2; ++kk2)
#pragma unroll
            for (int fc = 0; fc < 4; ++fc)
                vv[kk2 * 4 + fc] =
                    *(const bf16x8*)(vb0 + (size_t)fc * 16 * 4096 + kk2 * 32);

        // ---- S = Q K^T from LDS, FOUR independent accumulator chains ----
        // (was 2 chains of 16 dependent MFMAs; accumulate-latency bound at
        //  2 waves/SIMD.  Chains of 8 -> 8 chains/SIMD.)
        f32x4 s00 = (f32x4){0.f, 0.f, 0.f, 0.f};
        f32x4 s01 = (f32x4){0.f, 0.f, 0.f, 0.f};
        f32x4 s10 = (f32x4){0.f, 0.f, 0.f, 0.f};
        f32x4 s11 = (f32x4){0.f, 0.f, 0.f, 0.f};
        const bf16* kr0 = Kc + (size_t)(par * 32 + lc) * 512 + xlo;
        const bf16* kr1 = kr0 + (size_t)16 * 512;
#pragma unroll
        for (int kp = 0; kp < 8; ++kp) {
            const int ktA = 2 * kp;
            const int ktB = 2 * kp + 1;
            const int offA = (ktA * 32) ^ xb2;
            const int offB = (ktB * 32) ^ xb2;
            bf16x8 k0a = *(const bf16x8*)(kr0 + offA);
            bf16x8 k0b = *(const bf16x8*)(kr0 + offB);
            bf16x8 k1a = *(const bf16x8*)(kr1 + offA);
            bf16x8 k1b = *(const bf16x8*)(kr1 + offB);
            s00 = MFMA16(qf[ktA], k0a, s00);
            s10 = MFMA16(qf[ktA], k1a, s10);
            s01 = MFMA16(qf[ktB], k0b, s01);
            s11 = MFMA16(qf[ktB], k1b, s11);
        }
        f32x4 s0, s1;
#pragma unroll
        for (int i = 0; i < 4; ++i) {
            s0[i] = s00[i] + s01[i];
            s1[i] = s10[i] + s11[i];
        }

        // ---- P = exp2(s*scale2) -> LDS, accumulate denominator per-lane ----
#pragma unroll
        for (int i = 0; i < 4; ++i) {
            const int row = qrb + lg * 4 + i;
            float p0 = __builtin_amdgcn_exp2f(s0[i] * scale2);
            float p1 = __builtin_amdgcn_exp2f(s1[i] * scale2);
            Pc[row * 72 + par * 32 + lc]      = (bf16)p0;
            Pc[row * 72 + par * 32 + 16 + lc] = (bf16)p1;
            Lacc[i] += p0 + p1;
        }

        __syncthreads();   // drains K-prefetch + V loads; P visible

        // ---- O += P * V (V from registers, P from padded LDS) ----
#pragma unroll
        for (int kk2 = 0; kk2 < 2; ++kk2) {
            bf16x8 pa[4];
#pragma unroll
            for (int fr = 0; fr < 4; ++fr)
                pa[fr] = *(const bf16x8*)&Pc[(fr * 16 + lc) * 72 + kk2 * 32 + lg * 8];
#pragma unroll
            for (int fc = 0; fc < 4; ++fc)
#pragma unroll
                for (int fr = 0; fr < 4; ++fr)
                    acc[fr][fc] = MFMA16(pa[fr], vv[kk2 * 4 + fc], acc[fr][fc]);
        }
    }

    // ---- denominator: reduce per-lane partials across the 16 lc lanes ----
#pragma unroll
    for (int d = 1; d < 16; d <<= 1)
#pragma unroll
        for (int i = 0; i < 4; ++i)
            Lacc[i] += __shfl_xor(Lacc[i], d);
    if (lc == 0)
#pragma unroll
        for (int i = 0; i < 4; ++i)
            l_part[qrb + lg * 4 + i][par] = Lacc[i];
    __syncthreads();

    // ---- epilogue: divide by denominator, store fp32 ----
    for (int fr = 0; fr < 4; ++fr) {
        float invl[4];
#pragma unroll
        for (int i = 0; i < 4; ++i) {
            const int row = fr * 16 + lg * 4 + i;
            invl[i] = 1.0f / (l_part[row][0] + l_part[row][1]);
        }
        for (int fc = 0; fc < 4; ++fc) {
            const size_t base =
                ((size_t)(b * 4096 + q0 + fr * 16 + lg * 4)) * 512 + w * 64 + fc * 16 + lc;
#pragma unroll
            for (int i = 0; i < 4; ++i)
                Out[base + (size_t)i * 512] = acc[fr][fc][i] * invl[i];
        }
    }
}

// ---------------------------------------------------------------------------
extern "C" void kernel_launch(void* const* d_in, const int* in_sizes, int n_in,
                              void* d_out, int out_size, void* d_ws, size_t ws_size,
                              hipStream_t stream) {
    const float* X    = (const float*)d_in[0];
    const float* Wq   = (const float*)d_in[1];
    const float* Wk   = (const float*)d_in[2];
    const float* Wv   = (const float*)d_in[3];
    const float* temp = (const float*)d_in[4];
    float* Out = (float*)d_out;

    const size_t NE = (size_t)4 * 4096 * 512;
    bf16* Qw = (bf16*)d_ws;
    bf16* Kw = Qw + NE;
    bf16* Vt = Kw + NE;

    proj_kernel<<<dim3(128, 4, 3), 256, 0, stream>>>(X, Wq, Wk, Wv, Qw, Kw, Vt);

    // dynamic LDS: 2 K-buffers (128 KiB) + 2 P-buffers (18 KiB) = 149504 B
    const size_t smem_bytes = (size_t)2 * 64 * 512 * 2 + (size_t)2 * 64 * 72 * 2;
    flash_kernel<<<dim3(64, 4), 512, smem_bytes, stream>>>(Qw, Kw, Vt, temp, Out);
}

// Round 11
// 286.637 us; speedup vs baseline: 1.4963x; 1.0019x over previous
//
#include <hip/hip_runtime.h>
#include <hip/hip_bf16.h>
#include <stdint.h>

typedef __bf16 bf16;
typedef bf16 bf16x8 __attribute__((ext_vector_type(8)));
typedef bf16 bf16x4 __attribute__((ext_vector_type(4)));
typedef float f32x4 __attribute__((ext_vector_type(4)));

#define MFMA16(a, b, c) __builtin_amdgcn_mfma_f32_16x16x32_bf16((a), (b), (c), 0, 0, 0)

// async 16B global->LDS (wave-uniform LDS base, per-lane global src)
__device__ __forceinline__ void async_ld16(bf16* lds, const bf16* g) {
    __builtin_amdgcn_global_load_lds(
        (const __attribute__((address_space(1))) void*)g,
        (__attribute__((address_space(3))) void*)lds, 16, 0, 0);
}

// ---------------------------------------------------------------------------
// Kernel 1: QKV projection.  C[M,N] = X[M,K] * W[N,K]^T  (x @ W.T), bf16 out.
// z = 0 -> Q (row-major), z = 1 -> K (row-major), z = 2 -> V transposed
// (Vt[b][e][s]) so the attention kernel's PV B-fragments are contiguous.
// ---------------------------------------------------------------------------
__global__ __launch_bounds__(256) void proj_kernel(
    const float* __restrict__ X,
    const float* __restrict__ Wq,
    const float* __restrict__ Wk,
    const float* __restrict__ Wv,
    bf16* __restrict__ Qo,
    bf16* __restrict__ Ko,
    bf16* __restrict__ Vt)
{
    __shared__ bf16 As[128][72];
    __shared__ bf16 Bs[128][72];

    const int z    = blockIdx.z;
    const float* W = (z == 0) ? Wq : (z == 1) ? Wk : Wv;
    const int row0 = blockIdx.x * 128;
    const int col0 = blockIdx.y * 128;

    const int t    = threadIdx.x;
    const int w    = t >> 6;
    const int lane = t & 63;
    const int lg   = lane >> 4;
    const int lc   = lane & 15;
    const int wr   = (w >> 1) * 64;
    const int wc   = (w & 1) * 64;

    const int srow = t >> 1;
    const int sd0  = (t & 1) * 16;

    f32x4 acc[4][4];
    for (int a = 0; a < 4; ++a)
        for (int b = 0; b < 4; ++b)
            acc[a][b] = (f32x4){0.f, 0.f, 0.f, 0.f};

    for (int kt = 0; kt < 16; ++kt) {
        const int k = kt * 32;
        __syncthreads();
        {
            const float* xs = X + (size_t)(row0 + srow) * 512 + k + sd0;
            float4 a0 = *(const float4*)(xs + 0);
            float4 a1 = *(const float4*)(xs + 4);
            float4 a2 = *(const float4*)(xs + 8);
            float4 a3 = *(const float4*)(xs + 12);
            bf16x8 h0 = { (bf16)a0.x, (bf16)a0.y, (bf16)a0.z, (bf16)a0.w,
                          (bf16)a1.x, (bf16)a1.y, (bf16)a1.z, (bf16)a1.w };
            bf16x8 h1 = { (bf16)a2.x, (bf16)a2.y, (bf16)a2.z, (bf16)a2.w,
                          (bf16)a3.x, (bf16)a3.y, (bf16)a3.z, (bf16)a3.w };
            *(bf16x8*)&As[srow][sd0]     = h0;
            *(bf16x8*)&As[srow][sd0 + 8] = h1;

            const float* ws_ = W + (size_t)(col0 + srow) * 512 + k + sd0;
            float4 b0 = *(const float4*)(ws_ + 0);
            float4 b1 = *(const float4*)(ws_ + 4);
            float4 b2 = *(const float4*)(ws_ + 8);
            float4 b3 = *(const float4*)(ws_ + 12);
            bf16x8 g0 = { (bf16)b0.x, (bf16)b0.y, (bf16)b0.z, (bf16)b0.w,
                          (bf16)b1.x, (bf16)b1.y, (bf16)b1.z, (bf16)b1.w };
            bf16x8 g1 = { (bf16)b2.x, (bf16)b2.y, (bf16)b2.z, (bf16)b2.w,
                          (bf16)b3.x, (bf16)b3.y, (bf16)b3.z, (bf16)b3.w };
            *(bf16x8*)&Bs[srow][sd0]     = g0;
            *(bf16x8*)&Bs[srow][sd0 + 8] = g1;
        }
        __syncthreads();

        bf16x8 af[4], bfr[4];
        for (int fr = 0; fr < 4; ++fr)
            af[fr] = *(const bf16x8*)&As[wr + fr * 16 + lc][lg * 8];
        for (int fc = 0; fc < 4; ++fc)
            bfr[fc] = *(const bf16x8*)&Bs[wc + fc * 16 + lc][lg * 8];
        for (int fr = 0; fr < 4; ++fr)
            for (int fc = 0; fc < 4; ++fc)
                acc[fr][fc] = MFMA16(af[fr], bfr[fc], acc[fr][fc]);
    }

    if (z < 2) {
        bf16* outp = (z == 0) ? Qo : Ko;
        for (int fr = 0; fr < 4; ++fr)
            for (int fc = 0; fc < 4; ++fc) {
                const int colg = col0 + wc + fc * 16 + lc;
                const int rowb = row0 + wr + fr * 16 + lg * 4;
                for (int i = 0; i < 4; ++i)
                    outp[(size_t)(rowb + i) * 512 + colg] = (bf16)acc[fr][fc][i];
            }
    } else {
        for (int fr = 0; fr < 4; ++fr)
            for (int fc = 0; fc < 4; ++fc) {
                const int e    = col0 + wc + fc * 16 + lc;
                const int rowb = row0 + wr + fr * 16 + lg * 4;
                const int bb   = rowb >> 12;
                const int sl   = rowb & 4095;
                bf16x4 v = { (bf16)acc[fr][fc][0], (bf16)acc[fr][fc][1],
                             (bf16)acc[fr][fc][2], (bf16)acc[fr][fc][3] };
                *(bf16x4*)&Vt[(((size_t)(bb * 512 + e)) << 12) + sl] = v;
            }
    }
}

// ---------------------------------------------------------------------------
// Kernel 2: flash attention, PRODUCER-CONSUMER WAVE SPECIALIZATION.
// 8 waves: waves 0-3 = PRODUCERS (each owns 16 q-rows): stage K (dbuf),
// QK^T from LDS, exp, write P (dbuf), accumulate L.  Waves 4-7 = CONSUMERS
// (each owns 128 e-cols): PV from P_lds + V-from-global into acc[4][8].
// ONE barrier per iter: producer QK(i) runs concurrently with consumer
// PV(i-1) on the same SIMDs (waves round-robin -> 1 producer + 1 consumer
// per SIMD).  P dbuf: A writes buf i&1 while B reads buf (i-1)&1 -> never
// the same buffer between consecutive barriers.  K dbuf is producer-private.
// Barrier counts: both paths execute 65 s_barriers + 1 final __syncthreads.
// All waves lgkmcnt(0) before each barrier (R8 lesson: barrier alone proves
// arrival, not LDS-read completion).
// ---------------------------------------------------------------------------
__global__ __launch_bounds__(512) void flash_kernel(
    const bf16* __restrict__ Q,
    const bf16* __restrict__ K,
    const bf16* __restrict__ Vt,
    const float* __restrict__ temp,
    float* __restrict__ Out)
{
    extern __shared__ char smem[];
    bf16* Kb = (bf16*)smem;                       // [2][64*512]  128 KiB
    bf16* Pb = (bf16*)(smem + 2 * 64 * 512 * 2);  // [2][64*72]   18 KiB
    __shared__ float l_part[64];

    const int b  = blockIdx.y;
    const int q0 = blockIdx.x * 64;
    const int t    = threadIdx.x;
    const int w    = t >> 6;               // wave 0..7
    const int lane = t & 63;
    const int lg   = lane >> 4;
    const int lc   = lane & 15;

    const float scale2 = temp[0] * 0.04419417382415922f * 1.4426950408889634f;

    const bf16* kbase = K  + (size_t)b * 4096 * 512;
    const bf16* vbase = Vt + (size_t)b * 512 * 4096;

    if (w < 4) {
        // ================= PRODUCER: QK^T + softmax-numerator =============
        // wave w owns q-rows [w*16, w*16+16) and stages K rows [w*16, w*16+16)
        // prologue: stage K tile 0 into buf 0 (16 rows, swizzled source)
#pragma unroll
        for (int j = 0; j < 16; ++j) {
            const int r = w * 16 + j;                 // r&7 == j&7
            async_ld16(Kb + (size_t)r * 512,
                       kbase + (size_t)r * 512 + ((lane ^ (j & 7)) << 3));
        }
        // Q fragments for rows q0 + w*16 + lc (64 VGPR), after K so the
        // manual vmcnt(16) below waits exactly the 16 K-stage loads.
        bf16x8 qf[16];
        {
            const bf16* qrow =
                Q + ((size_t)(b * 4096 + q0 + w * 16 + lc)) * 512 + lg * 8;
#pragma unroll
            for (int kt = 0; kt < 16; ++kt)
                qf[kt] = *(const bf16x8*)(qrow + kt * 32);
        }
        float Lacc[4] = {0.f, 0.f, 0.f, 0.f};

        asm volatile("s_waitcnt vmcnt(16)" ::: "memory");  // K(0) staged
        __builtin_amdgcn_s_barrier();                      // barrier #0

        const int r7  = lc & 7;
        const int xlo = (lg ^ (r7 & 3)) << 3;
        const int xb2 = (r7 & 4) << 3;

        for (int it = 0; it < 64; ++it) {
            const int cur = it & 1;
            const bf16* Kc = Kb + (size_t)cur * 32768;
            bf16*       Pc = Pb + (size_t)cur * (64 * 72);

            // stage K(it+1) into the other buffer (full iter to land)
            if (it < 63) {
                bf16* Kn = Kb + (size_t)(cur ^ 1) * 32768;
                const bf16* knx = kbase + (size_t)(it + 1) * 64 * 512;
#pragma unroll
                for (int j = 0; j < 16; ++j) {
                    const int r = w * 16 + j;
                    async_ld16(Kn + (size_t)r * 512,
                               knx + (size_t)r * 512 + ((lane ^ (j & 7)) << 3));
                }
            }

            // S = Q K^T: 16 q-rows x 64 k-cols, 4 independent chains
            f32x4 s[4];
#pragma unroll
            for (int fc = 0; fc < 4; ++fc)
                s[fc] = (f32x4){0.f, 0.f, 0.f, 0.f};
            const bf16* kr0 = Kc + (size_t)lc * 512 + xlo;
#pragma unroll
            for (int kt = 0; kt < 16; ++kt) {
                const int off = (kt * 32) ^ xb2;
#pragma unroll
                for (int fc = 0; fc < 4; ++fc) {
                    bf16x8 kf = *(const bf16x8*)(kr0 + (size_t)fc * 8192 + off);
                    s[fc] = MFMA16(qf[kt], kf, s[fc]);
                }
            }

            // P = exp2(s*scale2) -> P_lds[cur], accumulate denominator
#pragma unroll
            for (int fc = 0; fc < 4; ++fc)
#pragma unroll
                for (int i = 0; i < 4; ++i) {
                    float p = __builtin_amdgcn_exp2f(s[fc][i] * scale2);
                    Pc[(w * 16 + lg * 4 + i) * 72 + fc * 16 + lc] = (bf16)p;
                    Lacc[i] += p;
                }

            // K-reads + P-writes architecturally complete; K(it+1) landed
            // (it had the whole QK+exp phase).
            asm volatile("s_waitcnt lgkmcnt(0) vmcnt(0)" ::: "memory");
            __builtin_amdgcn_s_barrier();              // barrier #(it+1)
        }

        // denominator: reduce across the 16 k-lanes (lc), publish
#pragma unroll
        for (int d = 1; d < 16; d <<= 1)
#pragma unroll
            for (int i = 0; i < 4; ++i)
                Lacc[i] += __shfl_xor(Lacc[i], d);
        if (lc == 0)
#pragma unroll
            for (int i = 0; i < 4; ++i)
                l_part[w * 16 + lg * 4 + i] = Lacc[i];
        __syncthreads();                               // final sync (#65)
    } else {
        // ================= CONSUMER: O += P * V ===========================
        const int wB = w - 4;                          // e-range wB*128
        f32x4 acc[4][8];
#pragma unroll
        for (int a = 0; a < 4; ++a)
#pragma unroll
            for (int c = 0; c < 8; ++c)
                acc[a][c] = (f32x4){0.f, 0.f, 0.f, 0.f};

        __builtin_amdgcn_s_barrier();                  // barrier #0

        // PV body for tile j (reads Pb[j&1], V from global)
#define PV_TILE(J)                                                             \
        {                                                                      \
            const bf16* Pc  = Pb + (size_t)((J) & 1) * (64 * 72);              \
            const bf16* vb0 = vbase + (size_t)(wB * 128 + lc) * 4096           \
                              + (J) * 64 + lg * 8;                             \
            bf16x8 vvA[8], vvB[8];                                             \
            _Pragma("unroll")                                                  \
            for (int fc = 0; fc < 8; ++fc) {                                   \
                vvA[fc] = *(const bf16x8*)(vb0 + (size_t)fc * 16 * 4096);      \
                vvB[fc] = *(const bf16x8*)(vb0 + (size_t)fc * 16 * 4096 + 32); \
            }                                                                  \
            bf16x8 pa[4];                                                      \
            _Pragma("unroll")                                                  \
            for (int fr = 0; fr < 4; ++fr)                                     \
                pa[fr] = *(const bf16x8*)&Pc[(fr * 16 + lc) * 72 + lg * 8];    \
            _Pragma("unroll")                                                  \
            for (int fc = 0; fc < 8; ++fc)                                     \
                _Pragma("unroll")                                              \
                for (int fr = 0; fr < 4; ++fr)                                 \
                    acc[fr][fc] = MFMA16(pa[fr], vvA[fc], acc[fr][fc]);        \
            _Pragma("unroll")                                                  \
            for (int fr = 0; fr < 4; ++fr)                                     \
                pa[fr] = *(const bf16x8*)&Pc[(fr * 16 + lc) * 72 + 32 + lg * 8]; \
            _Pragma("unroll")                                                  \
            for (int fc = 0; fc < 8; ++fc)                                     \
                _Pragma("unroll")                                              \
                for (int fr = 0; fr < 4; ++fr)                                 \
                    acc[fr][fc] = MFMA16(pa[fr], vvB[fc], acc[fr][fc]);        \
        }

        for (int it = 0; it < 64; ++it) {
            if (it > 0) PV_TILE(it - 1)
            // P-reads complete before licensing A to overwrite that buffer
            asm volatile("s_waitcnt lgkmcnt(0)" ::: "memory");
            __builtin_amdgcn_s_barrier();              // barrier #(it+1)
        }
        PV_TILE(63)
#undef PV_TILE

        __syncthreads();                               // final sync (#65)

        // epilogue: normalize and store this wave's 64q x 128e chunk
        for (int fr = 0; fr < 4; ++fr) {
            float invl[4];
#pragma unroll
            for (int i = 0; i < 4; ++i)
                invl[i] = 1.0f / l_part[fr * 16 + lg * 4 + i];
            for (int fc = 0; fc < 8; ++fc) {
                const size_t base =
                    ((size_t)(b * 4096 + q0 + fr * 16 + lg * 4)) * 512 +
                    wB * 128 + fc * 16 + lc;
#pragma unroll
                for (int i = 0; i < 4; ++i)
                    Out[base + (size_t)i * 512] = acc[fr][fc][i] * invl[i];
            }
        }
    }
}

// ---------------------------------------------------------------------------
extern "C" void kernel_launch(void* const* d_in, const int* in_sizes, int n_in,
                              void* d_out, int out_size, void* d_ws, size_t ws_size,
                              hipStream_t stream) {
    const float* X    = (const float*)d_in[0];
    const float* Wq   = (const float*)d_in[1];
    const float* Wk   = (const float*)d_in[2];
    const float* Wv   = (const float*)d_in[3];
    const float* temp = (const float*)d_in[4];
    float* Out = (float*)d_out;

    const size_t NE = (size_t)4 * 4096 * 512;
    bf16* Qw = (bf16*)d_ws;
    bf16* Kw = Qw + NE;
    bf16* Vt = Kw + NE;

    proj_kernel<<<dim3(128, 4, 3), 256, 0, stream>>>(X, Wq, Wk, Wv, Qw, Kw, Vt);

    // dynamic LDS: 2 K-buffers (128 KiB) + 2 P-buffers (18 KiB) = 149504 B
    const size_t smem_bytes = (size_t)2 * 64 * 512 * 2 + (size_t)2 * 64 * 72 * 2;
    flash_kernel<<<dim3(64, 4), 512, smem_bytes, stream>>>(Qw, Kw, Vt, temp, Out);
}